// Round 1
// baseline (421.313 us; speedup 1.0000x reference)
//
#include <hip/hip_runtime.h>
#include <hip/hip_bf16.h>
#include <stdint.h>

#define B_ROWS 16384
#define IN_DIM 2048
#define OUT_DIM 2048

typedef __attribute__((ext_vector_type(4))) float f32x4;
typedef __attribute__((ext_vector_type(8))) short s16x8;

__device__ __forceinline__ unsigned short f2bf_rne(float f) {
  union { float f; unsigned u; } c; c.f = f;
  unsigned u = c.u;
  return (unsigned short)((u + 0x7FFFu + ((u >> 16) & 1u)) >> 16);
}

// One block per row: convert row to bf16 (raw, unnormalized) and compute
// scale[row] = 1/(||x_row||_2 + 1e-4) in fp32.
__global__ void __launch_bounds__(256) prep_x_kernel(const float* __restrict__ x,
                                                     unsigned short* __restrict__ xn,
                                                     float* __restrict__ scale) {
  const int row = blockIdx.x;
  const int t = threadIdx.x;
  const float4* xr = (const float4*)(x + (size_t)row * IN_DIM);
  float4 v0 = xr[t * 2 + 0];
  float4 v1 = xr[t * 2 + 1];
  float ss = v0.x * v0.x + v0.y * v0.y + v0.z * v0.z + v0.w * v0.w +
             v1.x * v1.x + v1.y * v1.y + v1.z * v1.z + v1.w * v1.w;
  s16x8 p;
  p[0] = (short)f2bf_rne(v0.x); p[1] = (short)f2bf_rne(v0.y);
  p[2] = (short)f2bf_rne(v0.z); p[3] = (short)f2bf_rne(v0.w);
  p[4] = (short)f2bf_rne(v1.x); p[5] = (short)f2bf_rne(v1.y);
  p[6] = (short)f2bf_rne(v1.z); p[7] = (short)f2bf_rne(v1.w);
  *(s16x8*)(xn + (size_t)row * IN_DIM + t * 8) = p;

  // wave reduce (64 lanes), then cross-wave via LDS
  #pragma unroll
  for (int off = 32; off > 0; off >>= 1) ss += __shfl_down(ss, off, 64);
  __shared__ float red[4];
  if ((t & 63) == 0) red[t >> 6] = ss;
  __syncthreads();
  if (t == 0) {
    float s = red[0] + red[1] + red[2] + red[3];
    scale[row] = 1.0f / (sqrtf(s) + 1e-4f);
  }
}

// W fp32 -> bf16, 8 elements per thread
__global__ void __launch_bounds__(256) prep_w_kernel(const float* __restrict__ W,
                                                     unsigned short* __restrict__ Wb) {
  const size_t base = (size_t)blockIdx.x * 2048 + (size_t)threadIdx.x * 8;
  const float4* wp = (const float4*)(W + base);
  float4 v0 = wp[0];
  float4 v1 = wp[1];
  s16x8 p;
  p[0] = (short)f2bf_rne(v0.x); p[1] = (short)f2bf_rne(v0.y);
  p[2] = (short)f2bf_rne(v0.z); p[3] = (short)f2bf_rne(v0.w);
  p[4] = (short)f2bf_rne(v1.x); p[5] = (short)f2bf_rne(v1.y);
  p[6] = (short)f2bf_rne(v1.z); p[7] = (short)f2bf_rne(v1.w);
  *(s16x8*)(Wb + base) = p;
}

// C[M,N] = relu( (A[M,K] . Wb[N,K]^T) * scale[M] + bias[N] )
// 128x128 block tile, BK=64, 4 waves in 2x2, each wave 64x64 via 4x4 MFMA 16x16x32.
__global__ void __launch_bounds__(256) gemm_kernel(const unsigned short* __restrict__ A,
                                                   const unsigned short* __restrict__ Bm,
                                                   const float* __restrict__ scale,
                                                   const float* __restrict__ bias,
                                                   float* __restrict__ out) {
  constexpr int BK = 64;
  __shared__ short As[128 * BK];  // row-major [128][64], no padding (global_load_lds)
  __shared__ short Bs[128 * BK];

  const int tid  = threadIdx.x;
  const int bn   = blockIdx.x;   // N tile (16)
  const int bm   = blockIdx.y;   // M tile (128)
  const int lane = tid & 63;
  const int wave = tid >> 6;
  const int wm   = wave >> 1;
  const int wn   = wave & 1;
  const int lrow = lane & 15;
  const int lq   = lane >> 4;

  // staging: thread t loads 16B = 8 bf16; row = t/8 (+32 per issue), col chunk = (t%8)*8
  const int ar = tid >> 3;
  const int ac = (tid & 7) * 8;
  const unsigned short* ag = A  + (size_t)(bm * 128 + ar) * IN_DIM + ac;
  const unsigned short* bg = Bm + (size_t)(bn * 128 + ar) * IN_DIM + ac;
  char* asl = (char*)As + tid * 16;
  char* bsl = (char*)Bs + tid * 16;

  f32x4 acc[4][4] = {};

  for (int k0 = 0; k0 < IN_DIM; k0 += BK) {
    #pragma unroll
    for (int i = 0; i < 4; ++i) {
      __builtin_amdgcn_global_load_lds(
          (const __attribute__((address_space(1))) unsigned int*)(ag + (size_t)i * 32 * IN_DIM),
          (__attribute__((address_space(3))) unsigned int*)(asl + i * 4096), 16, 0, 0);
    }
    #pragma unroll
    for (int i = 0; i < 4; ++i) {
      __builtin_amdgcn_global_load_lds(
          (const __attribute__((address_space(1))) unsigned int*)(bg + (size_t)i * 32 * IN_DIM),
          (__attribute__((address_space(3))) unsigned int*)(bsl + i * 4096), 16, 0, 0);
    }
    ag += BK;
    bg += BK;
    __syncthreads();  // compiler emits vmcnt(0) drain here

    #pragma unroll
    for (int kk = 0; kk < 2; ++kk) {
      s16x8 af[4], bf[4];
      #pragma unroll
      for (int mi = 0; mi < 4; ++mi)
        af[mi] = *(const s16x8*)(As + (wm * 64 + mi * 16 + lrow) * BK + kk * 32 + lq * 8);
      #pragma unroll
      for (int ni = 0; ni < 4; ++ni)
        bf[ni] = *(const s16x8*)(Bs + (wn * 64 + ni * 16 + lrow) * BK + kk * 32 + lq * 8);
      #pragma unroll
      for (int mi = 0; mi < 4; ++mi)
        #pragma unroll
        for (int ni = 0; ni < 4; ++ni)
          acc[mi][ni] = __builtin_amdgcn_mfma_f32_16x16x32_bf16(af[mi], bf[ni], acc[mi][ni], 0, 0, 0);
    }
    __syncthreads();
  }

  // epilogue: D[m][n] lane map: col = lane&15, row = (lane>>4)*4 + r
  const int row0 = bm * 128 + wm * 64 + lq * 4;
  const int col0 = bn * 128 + wn * 64 + lrow;
  #pragma unroll
  for (int mi = 0; mi < 4; ++mi) {
    const int row = row0 + mi * 16;
    const f32x4 sc = *(const f32x4*)(scale + row);  // rows row..row+3
    #pragma unroll
    for (int ni = 0; ni < 4; ++ni) {
      const int col = col0 + ni * 16;
      const float bcol = bias[col];
      #pragma unroll
      for (int r = 0; r < 4; ++r) {
        float v = acc[mi][ni][r] * sc[r] + bcol;
        out[(size_t)(row + r) * OUT_DIM + col] = fmaxf(v, 0.0f);
      }
    }
  }
}

extern "C" void kernel_launch(void* const* d_in, const int* in_sizes, int n_in,
                              void* d_out, int out_size, void* d_ws, size_t ws_size,
                              hipStream_t stream) {
  const float* x = (const float*)d_in[0];
  const float* W = (const float*)d_in[1];
  const float* b = (const float*)d_in[2];
  float* out = (float*)d_out;

  char* ws = (char*)d_ws;
  unsigned short* xn    = (unsigned short*)ws;                                  // 67108864 B
  unsigned short* Wb    = (unsigned short*)(ws + (size_t)67108864);             //  8388608 B
  float*          scale = (float*)(ws + (size_t)67108864 + (size_t)8388608);    //    65536 B

  prep_x_kernel<<<B_ROWS, 256, 0, stream>>>(x, xn, scale);
  prep_w_kernel<<<(OUT_DIM * IN_DIM) / 2048, 256, 0, stream>>>(W, Wb);

  dim3 grid(OUT_DIM / 128, B_ROWS / 128);
  gemm_kernel<<<grid, 256, 0, stream>>>(xn, Wb, scale, b, out);
}

// Round 3
// 381.502 us; speedup vs baseline: 1.1044x; 1.1044x over previous
//
#include <hip/hip_runtime.h>
#include <hip/hip_bf16.h>
#include <stdint.h>

#define B_ROWS 16384
#define IN_DIM 2048
#define OUT_DIM 2048

typedef __attribute__((ext_vector_type(4))) float f32x4;
typedef __attribute__((ext_vector_type(8))) short s16x8;

__device__ __forceinline__ unsigned short f2bf_rne(float f) {
  union { float f; unsigned u; } c; c.f = f;
  unsigned u = c.u;
  return (unsigned short)((u + 0x7FFFu + ((u >> 16) & 1u)) >> 16);
}

// One WAVE per row: convert the FULL 2048-float row to bf16 (raw, unnormalized)
// and compute scale[row] = 1/(||x_row||_2 + 1e-4) in fp32.
// Each lane handles 4 chunks of 32 B (2 float4) => 64 lanes * 32 floats = 2048.
// No LDS, no __syncthreads.
__global__ void __launch_bounds__(256) prep_x_kernel(const float* __restrict__ x,
                                                     unsigned short* __restrict__ xn,
                                                     float* __restrict__ scale) {
  const int row  = (blockIdx.x * 256 + threadIdx.x) >> 6;
  const int lane = threadIdx.x & 63;
  const float4* xr = (const float4*)(x + (size_t)row * IN_DIM);
  unsigned short* xrow = xn + (size_t)row * IN_DIM;

  float ss = 0.0f;
  #pragma unroll
  for (int j = 0; j < 4; ++j) {
    const int f4 = j * 128 + lane * 2;   // float4 index within the row
    float4 v0 = xr[f4 + 0];
    float4 v1 = xr[f4 + 1];
    ss += v0.x * v0.x + v0.y * v0.y + v0.z * v0.z + v0.w * v0.w +
          v1.x * v1.x + v1.y * v1.y + v1.z * v1.z + v1.w * v1.w;
    s16x8 p;
    p[0] = (short)f2bf_rne(v0.x); p[1] = (short)f2bf_rne(v0.y);
    p[2] = (short)f2bf_rne(v0.z); p[3] = (short)f2bf_rne(v0.w);
    p[4] = (short)f2bf_rne(v1.x); p[5] = (short)f2bf_rne(v1.y);
    p[6] = (short)f2bf_rne(v1.z); p[7] = (short)f2bf_rne(v1.w);
    *(s16x8*)(xrow + f4 * 4) = p;
  }

  // wave butterfly reduction, 64 lanes
  #pragma unroll
  for (int m = 32; m > 0; m >>= 1) ss += __shfl_xor(ss, m, 64);
  if (lane == 0) scale[row] = 1.0f / (sqrtf(ss) + 1e-4f);
}

// W fp32 -> bf16, 8 elements per thread
__global__ void __launch_bounds__(256) prep_w_kernel(const float* __restrict__ W,
                                                     unsigned short* __restrict__ Wb) {
  const size_t base = (size_t)blockIdx.x * 2048 + (size_t)threadIdx.x * 8;
  const float4* wp = (const float4*)(W + base);
  float4 v0 = wp[0];
  float4 v1 = wp[1];
  s16x8 p;
  p[0] = (short)f2bf_rne(v0.x); p[1] = (short)f2bf_rne(v0.y);
  p[2] = (short)f2bf_rne(v0.z); p[3] = (short)f2bf_rne(v0.w);
  p[4] = (short)f2bf_rne(v1.x); p[5] = (short)f2bf_rne(v1.y);
  p[6] = (short)f2bf_rne(v1.z); p[7] = (short)f2bf_rne(v1.w);
  *(s16x8*)(Wb + base) = p;
}

// C[M,N] = relu( (A[M,K] . Wb[N,K]^T) * scale[M] + bias[N] )
// 128x128 block tile, BK=64, 4 waves in 2x2, each wave 64x64 via 4x4 MFMA 16x16x32.
// LDS layout XOR-swizzled: physical chunk p at row r holds logical chunk p^(r&7).
// Swizzle applied on the global-read side (global_load_lds dest is lane-contiguous).
__global__ void __launch_bounds__(256) gemm_kernel(const unsigned short* __restrict__ A,
                                                   const unsigned short* __restrict__ Bm,
                                                   const float* __restrict__ scale,
                                                   const float* __restrict__ bias,
                                                   float* __restrict__ out) {
  constexpr int BK = 64;
  __shared__ short As[128 * BK];  // [128][8 chunks of 8 bf16], chunk-swizzled
  __shared__ short Bs[128 * BK];

  const int tid  = threadIdx.x;
  const int bn   = blockIdx.x;   // N tile (16)
  const int bm   = blockIdx.y;   // M tile (128)
  const int lane = tid & 63;
  const int wave = tid >> 6;
  const int wm   = wave >> 1;
  const int wn   = wave & 1;
  const int lrow = lane & 15;
  const int lq   = lane >> 4;

  // staging: thread t's LDS slot = row (t>>3), phys chunk (t&7).
  // It must load the logical chunk (t&7) ^ (row&7) from global.
  const int ar = tid >> 3;                          // 0..31, +32 per issue (keeps ar&7)
  const int ac = ((tid & 7) ^ (ar & 7)) * 8;        // swizzled source chunk
  const unsigned short* ag = A  + (size_t)(bm * 128 + ar) * IN_DIM + ac;
  const unsigned short* bg = Bm + (size_t)(bn * 128 + ar) * IN_DIM + ac;
  char* asl = (char*)As + tid * 16;
  char* bsl = (char*)Bs + tid * 16;

  f32x4 acc[4][4] = {};

  for (int k0 = 0; k0 < IN_DIM; k0 += BK) {
    #pragma unroll
    for (int i = 0; i < 4; ++i) {
      __builtin_amdgcn_global_load_lds(
          (const __attribute__((address_space(1))) unsigned int*)(ag + (size_t)i * 32 * IN_DIM),
          (__attribute__((address_space(3))) unsigned int*)(asl + i * 4096), 16, 0, 0);
    }
    #pragma unroll
    for (int i = 0; i < 4; ++i) {
      __builtin_amdgcn_global_load_lds(
          (const __attribute__((address_space(1))) unsigned int*)(bg + (size_t)i * 32 * IN_DIM),
          (__attribute__((address_space(3))) unsigned int*)(bsl + i * 4096), 16, 0, 0);
    }
    ag += BK;
    bg += BK;
    __syncthreads();  // compiler emits vmcnt(0) drain here

    #pragma unroll
    for (int kk = 0; kk < 2; ++kk) {
      s16x8 af[4], bf[4];
      #pragma unroll
      for (int mi = 0; mi < 4; ++mi) {
        const int R = wm * 64 + mi * 16 + lrow;
        af[mi] = *(const s16x8*)(As + R * BK + (((kk * 4 + lq) ^ (lrow & 7)) * 8));
      }
      #pragma unroll
      for (int ni = 0; ni < 4; ++ni) {
        const int R = wn * 64 + ni * 16 + lrow;
        bf[ni] = *(const s16x8*)(Bs + R * BK + (((kk * 4 + lq) ^ (lrow & 7)) * 8));
      }
      #pragma unroll
      for (int mi = 0; mi < 4; ++mi)
        #pragma unroll
        for (int ni = 0; ni < 4; ++ni)
          acc[mi][ni] = __builtin_amdgcn_mfma_f32_16x16x32_bf16(af[mi], bf[ni], acc[mi][ni], 0, 0, 0);
    }
    __syncthreads();
  }

  // epilogue: D[m][n] lane map: col = lane&15, row = (lane>>4)*4 + r
  const int row0 = bm * 128 + wm * 64 + lq * 4;
  const int col0 = bn * 128 + wn * 64 + lrow;
  #pragma unroll
  for (int mi = 0; mi < 4; ++mi) {
    const int row = row0 + mi * 16;
    const f32x4 sc = *(const f32x4*)(scale + row);  // rows row..row+3
    #pragma unroll
    for (int ni = 0; ni < 4; ++ni) {
      const int col = col0 + ni * 16;
      const float bcol = bias[col];
      #pragma unroll
      for (int r = 0; r < 4; ++r) {
        float v = acc[mi][ni][r] * sc[r] + bcol;
        out[(size_t)(row + r) * OUT_DIM + col] = fmaxf(v, 0.0f);
      }
    }
  }
}

extern "C" void kernel_launch(void* const* d_in, const int* in_sizes, int n_in,
                              void* d_out, int out_size, void* d_ws, size_t ws_size,
                              hipStream_t stream) {
  const float* x = (const float*)d_in[0];
  const float* W = (const float*)d_in[1];
  const float* b = (const float*)d_in[2];
  float* out = (float*)d_out;

  char* ws = (char*)d_ws;
  unsigned short* xn    = (unsigned short*)ws;                                  // 67108864 B
  unsigned short* Wb    = (unsigned short*)(ws + (size_t)67108864);             //  8388608 B
  float*          scale = (float*)(ws + (size_t)67108864 + (size_t)8388608);    //    65536 B

  prep_x_kernel<<<B_ROWS / 4, 256, 0, stream>>>(x, xn, scale);
  prep_w_kernel<<<(OUT_DIM * IN_DIM) / 2048, 256, 0, stream>>>(W, Wb);

  dim3 grid(OUT_DIM / 128, B_ROWS / 128);
  gemm_kernel<<<grid, 256, 0, stream>>>(xn, Wb, scale, b, out);
}

// Round 4
// 372.420 us; speedup vs baseline: 1.1313x; 1.0244x over previous
//
#include <hip/hip_runtime.h>
#include <hip/hip_bf16.h>
#include <stdint.h>

#define B_ROWS 16384
#define IN_DIM 2048
#define OUT_DIM 2048

typedef __attribute__((ext_vector_type(4))) float f32x4;
typedef __attribute__((ext_vector_type(8))) short s16x8;

__device__ __forceinline__ unsigned short f2bf_rne(float f) {
  union { float f; unsigned u; } c; c.f = f;
  unsigned u = c.u;
  return (unsigned short)((u + 0x7FFFu + ((u >> 16) & 1u)) >> 16);
}

// Fused prep: blocks [0, 4096) handle x (one WAVE per row: bf16 cast + L2 norm);
// blocks [4096, 6144) handle W (fp32 -> bf16, 8 elems/thread).
#define PREP_X_BLOCKS 4096
#define PREP_W_BLOCKS 2048

__global__ void __launch_bounds__(256) prep_kernel(const float* __restrict__ x,
                                                   unsigned short* __restrict__ xn,
                                                   float* __restrict__ scale,
                                                   const float* __restrict__ W,
                                                   unsigned short* __restrict__ Wb) {
  if (blockIdx.x < PREP_X_BLOCKS) {
    const int row  = (blockIdx.x * 256 + threadIdx.x) >> 6;
    const int lane = threadIdx.x & 63;
    const float4* xr = (const float4*)(x + (size_t)row * IN_DIM);
    unsigned short* xrow = xn + (size_t)row * IN_DIM;

    float ss = 0.0f;
    #pragma unroll
    for (int j = 0; j < 4; ++j) {
      const int f4 = j * 128 + lane * 2;   // float4 index within the row
      float4 v0 = xr[f4 + 0];
      float4 v1 = xr[f4 + 1];
      ss += v0.x * v0.x + v0.y * v0.y + v0.z * v0.z + v0.w * v0.w +
            v1.x * v1.x + v1.y * v1.y + v1.z * v1.z + v1.w * v1.w;
      s16x8 p;
      p[0] = (short)f2bf_rne(v0.x); p[1] = (short)f2bf_rne(v0.y);
      p[2] = (short)f2bf_rne(v0.z); p[3] = (short)f2bf_rne(v0.w);
      p[4] = (short)f2bf_rne(v1.x); p[5] = (short)f2bf_rne(v1.y);
      p[6] = (short)f2bf_rne(v1.z); p[7] = (short)f2bf_rne(v1.w);
      *(s16x8*)(xrow + f4 * 4) = p;
    }

    #pragma unroll
    for (int m = 32; m > 0; m >>= 1) ss += __shfl_xor(ss, m, 64);
    if (lane == 0) scale[row] = 1.0f / (sqrtf(ss) + 1e-4f);
  } else {
    const size_t base = (size_t)(blockIdx.x - PREP_X_BLOCKS) * 2048 +
                        (size_t)threadIdx.x * 8;
    const float4* wp = (const float4*)(W + base);
    float4 v0 = wp[0];
    float4 v1 = wp[1];
    s16x8 p;
    p[0] = (short)f2bf_rne(v0.x); p[1] = (short)f2bf_rne(v0.y);
    p[2] = (short)f2bf_rne(v0.z); p[3] = (short)f2bf_rne(v0.w);
    p[4] = (short)f2bf_rne(v1.x); p[5] = (short)f2bf_rne(v1.y);
    p[6] = (short)f2bf_rne(v1.z); p[7] = (short)f2bf_rne(v1.w);
    *(s16x8*)(Wb + base) = p;
  }
}

// C[M,N] = relu( (A[M,K] . Wb[N,K]^T) * scale[M] + bias[N] )
// 128x128 block tile, BK=64, 4 waves in 2x2, each wave 64x64 via 4x4 MFMA 16x16x32.
// LDS layout XOR-swizzled: physical chunk p at row r holds logical chunk p^(r&7),
// applied on the global-read side (global_load_lds dest is lane-contiguous).
// 1-D grid with GROUP_M=8 XCD swizzle: bid%8 == XCD (round-robin dispatch), so each
// XCD keeps ONE A-slab (512 KB) resident in its L2 per group while sweeping bn.
__global__ void __launch_bounds__(256) gemm_kernel(const unsigned short* __restrict__ A,
                                                   const unsigned short* __restrict__ Bm,
                                                   const float* __restrict__ scale,
                                                   const float* __restrict__ bias,
                                                   float* __restrict__ out) {
  constexpr int BK = 64;
  __shared__ short As[128 * BK];  // [128][8 chunks of 8 bf16], chunk-swizzled
  __shared__ short Bs[128 * BK];

  const int tid = threadIdx.x;
  // GROUP_M=8 swizzle: 16 groups of 8 bm-rows x 16 bn-cols = 128 tiles/group.
  const int bid   = blockIdx.x;
  const int group = bid >> 7;            // /128
  const int w_    = bid & 127;
  const int bm    = group * 8 + (w_ & 7);
  const int bn    = w_ >> 3;

  const int lane = tid & 63;
  const int wave = tid >> 6;
  const int wm   = wave >> 1;
  const int wn   = wave & 1;
  const int lrow = lane & 15;
  const int lq   = lane >> 4;

  // staging: thread t's LDS slot = row (t>>3), phys chunk (t&7).
  // It must load the logical chunk (t&7) ^ (row&7) from global.
  const int ar = tid >> 3;                          // 0..31, +32 per issue (keeps ar&7)
  const int ac = ((tid & 7) ^ (ar & 7)) * 8;        // swizzled source chunk
  const unsigned short* ag = A  + (size_t)(bm * 128 + ar) * IN_DIM + ac;
  const unsigned short* bg = Bm + (size_t)(bn * 128 + ar) * IN_DIM + ac;
  char* asl = (char*)As + tid * 16;
  char* bsl = (char*)Bs + tid * 16;

  f32x4 acc[4][4] = {};

  for (int k0 = 0; k0 < IN_DIM; k0 += BK) {
    #pragma unroll
    for (int i = 0; i < 4; ++i) {
      __builtin_amdgcn_global_load_lds(
          (const __attribute__((address_space(1))) unsigned int*)(ag + (size_t)i * 32 * IN_DIM),
          (__attribute__((address_space(3))) unsigned int*)(asl + i * 4096), 16, 0, 0);
    }
    #pragma unroll
    for (int i = 0; i < 4; ++i) {
      __builtin_amdgcn_global_load_lds(
          (const __attribute__((address_space(1))) unsigned int*)(bg + (size_t)i * 32 * IN_DIM),
          (__attribute__((address_space(3))) unsigned int*)(bsl + i * 4096), 16, 0, 0);
    }
    ag += BK;
    bg += BK;
    __syncthreads();  // compiler emits vmcnt(0) drain here

    #pragma unroll
    for (int kk = 0; kk < 2; ++kk) {
      s16x8 af[4], bf[4];
      #pragma unroll
      for (int mi = 0; mi < 4; ++mi) {
        const int R = wm * 64 + mi * 16 + lrow;
        af[mi] = *(const s16x8*)(As + R * BK + (((kk * 4 + lq) ^ (lrow & 7)) * 8));
      }
      #pragma unroll
      for (int ni = 0; ni < 4; ++ni) {
        const int R = wn * 64 + ni * 16 + lrow;
        bf[ni] = *(const s16x8*)(Bs + R * BK + (((kk * 4 + lq) ^ (lrow & 7)) * 8));
      }
      #pragma unroll
      for (int mi = 0; mi < 4; ++mi)
        #pragma unroll
        for (int ni = 0; ni < 4; ++ni)
          acc[mi][ni] = __builtin_amdgcn_mfma_f32_16x16x32_bf16(af[mi], bf[ni], acc[mi][ni], 0, 0, 0);
    }
    __syncthreads();
  }

  // epilogue: D[m][n] lane map: col = lane&15, row = (lane>>4)*4 + r
  const int row0 = bm * 128 + wm * 64 + lq * 4;
  const int col0 = bn * 128 + wn * 64 + lrow;
  #pragma unroll
  for (int mi = 0; mi < 4; ++mi) {
    const int row = row0 + mi * 16;
    const f32x4 sc = *(const f32x4*)(scale + row);  // rows row..row+3
    #pragma unroll
    for (int ni = 0; ni < 4; ++ni) {
      const int col = col0 + ni * 16;
      const float bcol = bias[col];
      #pragma unroll
      for (int r = 0; r < 4; ++r) {
        float v = acc[mi][ni][r] * sc[r] + bcol;
        out[(size_t)(row + r) * OUT_DIM + col] = fmaxf(v, 0.0f);
      }
    }
  }
}

extern "C" void kernel_launch(void* const* d_in, const int* in_sizes, int n_in,
                              void* d_out, int out_size, void* d_ws, size_t ws_size,
                              hipStream_t stream) {
  const float* x = (const float*)d_in[0];
  const float* W = (const float*)d_in[1];
  const float* b = (const float*)d_in[2];
  float* out = (float*)d_out;

  char* ws = (char*)d_ws;
  unsigned short* xn    = (unsigned short*)ws;                                  // 67108864 B
  unsigned short* Wb    = (unsigned short*)(ws + (size_t)67108864);             //  8388608 B
  float*          scale = (float*)(ws + (size_t)67108864 + (size_t)8388608);    //    65536 B

  prep_kernel<<<PREP_X_BLOCKS + PREP_W_BLOCKS, 256, 0, stream>>>(x, xn, scale, W, Wb);

  gemm_kernel<<<(OUT_DIM / 128) * (B_ROWS / 128), 256, 0, stream>>>(xn, Wb, scale, b, out);
}